// Round 2
// baseline (3341.246 us; speedup 1.0000x reference)
//
#include <hip/hip_runtime.h>

// GCN 2-layer fused kernel, fp32 exact-dtype version.
// B=4096, N=116, C_IN=116, H=128.
//
// Math (per batch):
//   d_i = rsqrt(1 + sum_k |a[i,k]|)
//   g'  = d ⊙ (f @ W1)                       (stage 2, into LDS)
//   h'  = d ⊙ relu(d ⊙ (Â @ g') + b1)        (stage 3; Â = |a|+I applied via
//                                             sum_k |a|·g' + g'[i])
//   v   = Â @ h'                             (stage 4, same code shape as 3)
//   out = relu(d ⊙ (v @ W2) + b2)            (stage 5)
// using A_norm @ (X W) == (Â @ (d⊙X)) @ W row-scaling commutation.

#define GN 116
#define GH 128

__global__ __launch_bounds__(512, 4) void gcn2_kernel(
    const float* __restrict__ a,
    const float* __restrict__ f,
    const float* __restrict__ W1,
    const float* __restrict__ b1,
    const float* __restrict__ W2,
    const float* __restrict__ b2,
    float* __restrict__ out)
{
    __shared__ float sX[GN * GH];   // 59392 B ping buffer: g' -> h' -> v
    __shared__ float sd[GN];

    const int t = threadIdx.x;
    const int b = blockIdx.x;
    const float* __restrict__ ab = a + (size_t)b * (GN * GN);
    const float* __restrict__ fb = f + (size_t)b * (GN * GN);

    // ---------------- Stage 1: d = rsqrt(1 + row-sum |a|) ----------------
    {
        const int r = t >> 2;       // 4 lanes per row
        const int s = t & 3;
        float sum = 0.0f;
        if (r < GN) {
            #pragma unroll
            for (int q = 0; q < 29; ++q)
                sum += fabsf(ab[r * GN + s + 4 * q]);
        }
        sum += __shfl_xor(sum, 1, 64);
        sum += __shfl_xor(sum, 2, 64);
        if (r < GN && s == 0)
            sd[r] = rsqrtf(sum + 1.0f);
    }
    __syncthreads();

    // Main layout: 128 column-threads x 4 row-groups; each thread owns 29 rows.
    const int c = t & 127;
    const int jg = __builtin_amdgcn_readfirstlane(t >> 7);  // wave-uniform

    float acc[29];

    // ---------------- Stage 2: sX = d ⊙ (f @ W1) ----------------
    #pragma unroll
    for (int q = 0; q < 29; ++q) acc[q] = 0.0f;

    #pragma unroll 1
    for (int mc = 0; mc < 29; ++mc) {
        const int m0 = mc * 4;
        const float w0 = W1[(m0 + 0) * GH + c];   // coalesced, L2-hot
        const float w1 = W1[(m0 + 1) * GH + c];
        const float w2 = W1[(m0 + 2) * GH + c];
        const float w3 = W1[(m0 + 3) * GH + c];
        #pragma unroll
        for (int q = 0; q < 29; ++q) {
            // wave-uniform address -> scalar load (broadcast)
            const float4 fv = *reinterpret_cast<const float4*>(fb + (jg + 4 * q) * GN + m0);
            float acq = acc[q];
            acq = fmaf(fv.x, w0, acq);
            acq = fmaf(fv.y, w1, acq);
            acq = fmaf(fv.z, w2, acq);
            acq = fmaf(fv.w, w3, acq);
            acc[q] = acq;
        }
    }
    #pragma unroll
    for (int q = 0; q < 29; ++q) {
        const int j = jg + 4 * q;
        sX[j * GH + c] = sd[j] * acc[q];
    }
    __syncthreads();

    // ---------------- Stage 3: h' = d ⊙ relu(d ⊙ (Â@g') + b1) ----------------
    #pragma unroll
    for (int q = 0; q < 29; ++q) acc[q] = 0.0f;

    #pragma unroll 1
    for (int kc = 0; kc < 29; ++kc) {
        const int k0 = kc * 4;
        const float x0 = sX[(k0 + 0) * GH + c];   // stride-1 across lanes: conflict-free
        const float x1 = sX[(k0 + 1) * GH + c];
        const float x2 = sX[(k0 + 2) * GH + c];
        const float x3 = sX[(k0 + 3) * GH + c];
        #pragma unroll
        for (int q = 0; q < 29; ++q) {
            const float4 av = *reinterpret_cast<const float4*>(ab + (jg + 4 * q) * GN + k0);
            float acq = acc[q];
            acq = fmaf(fabsf(av.x), x0, acq);     // abs folds into VOP3 input modifier
            acq = fmaf(fabsf(av.y), x1, acq);
            acq = fmaf(fabsf(av.z), x2, acq);
            acq = fmaf(fabsf(av.w), x3, acq);
            acc[q] = acq;
        }
    }
    {
        const float b1v = b1[c];
        #pragma unroll
        for (int q = 0; q < 29; ++q) {
            const int i = jg + 4 * q;
            const float di = sd[i];
            const float tt = acc[q] + sX[i * GH + c];        // + I term
            const float h = fmaxf(fmaf(di, tt, b1v), 0.0f);
            acc[q] = di * h;                                 // h'
        }
    }
    __syncthreads();
    #pragma unroll
    for (int q = 0; q < 29; ++q)
        sX[(jg + 4 * q) * GH + c] = acc[q];
    __syncthreads();

    // ---------------- Stage 4: v = Â @ h' ----------------
    #pragma unroll
    for (int q = 0; q < 29; ++q) acc[q] = 0.0f;

    #pragma unroll 1
    for (int kc = 0; kc < 29; ++kc) {
        const int k0 = kc * 4;
        const float x0 = sX[(k0 + 0) * GH + c];
        const float x1 = sX[(k0 + 1) * GH + c];
        const float x2 = sX[(k0 + 2) * GH + c];
        const float x3 = sX[(k0 + 3) * GH + c];
        #pragma unroll
        for (int q = 0; q < 29; ++q) {
            const float4 av = *reinterpret_cast<const float4*>(ab + (jg + 4 * q) * GN + k0);
            float acq = acc[q];
            acq = fmaf(fabsf(av.x), x0, acq);
            acq = fmaf(fabsf(av.y), x1, acq);
            acq = fmaf(fabsf(av.z), x2, acq);
            acq = fmaf(fabsf(av.w), x3, acq);
            acc[q] = acq;
        }
    }
    #pragma unroll
    for (int q = 0; q < 29; ++q)
        acc[q] += sX[(jg + 4 * q) * GH + c];                 // + I term
    __syncthreads();
    #pragma unroll
    for (int q = 0; q < 29; ++q)
        sX[(jg + 4 * q) * GH + c] = acc[q];
    __syncthreads();

    // ---------------- Stage 5: out = relu(d ⊙ (v @ W2) + b2) ----------------
    // Remap: 32 column-threads x 16 row-groups, 4 columns x <=8 rows per thread.
    {
        const int c4 = t & 31;
        const int jg4 = t >> 5;                 // 0..15 (two groups per wave)

        float o[8][4];
        #pragma unroll
        for (int q = 0; q < 8; ++q)
            #pragma unroll
            for (int u = 0; u < 4; ++u) o[q][u] = 0.0f;

        #pragma unroll 1
        for (int mc = 0; mc < 32; ++mc) {
            const int m0 = mc * 4;
            float w[4][4];
            #pragma unroll
            for (int mm = 0; mm < 4; ++mm)
                #pragma unroll
                for (int u = 0; u < 4; ++u)
                    w[mm][u] = W2[(m0 + mm) * GH + c4 + 32 * u];
            #pragma unroll
            for (int q = 0; q < 8; ++q) {
                if (q < 7 || jg4 < 4) {         // row 112..115 only for jg4<4
                    const int i = jg4 + 16 * q;
                    const float4 vv = *reinterpret_cast<const float4*>(&sX[i * GH + m0]);
                    #pragma unroll
                    for (int u = 0; u < 4; ++u) {
                        float oq = o[q][u];
                        oq = fmaf(vv.x, w[0][u], oq);
                        oq = fmaf(vv.y, w[1][u], oq);
                        oq = fmaf(vv.z, w[2][u], oq);
                        oq = fmaf(vv.w, w[3][u], oq);
                        o[q][u] = oq;
                    }
                }
            }
        }

        float* __restrict__ ob = out + (size_t)b * (GN * GH);
        float bb[4];
        #pragma unroll
        for (int u = 0; u < 4; ++u) bb[u] = b2[c4 + 32 * u];
        #pragma unroll
        for (int q = 0; q < 8; ++q) {
            if (q < 7 || jg4 < 4) {
                const int i = jg4 + 16 * q;
                const float di = sd[i];
                #pragma unroll
                for (int u = 0; u < 4; ++u)
                    ob[i * GH + c4 + 32 * u] = fmaxf(fmaf(di, o[q][u], bb[u]), 0.0f);
            }
        }
    }
}

extern "C" void kernel_launch(void* const* d_in, const int* in_sizes, int n_in,
                              void* d_out, int out_size, void* d_ws, size_t ws_size,
                              hipStream_t stream) {
    const float* a  = (const float*)d_in[0];
    const float* f  = (const float*)d_in[1];
    const float* W1 = (const float*)d_in[2];
    const float* b1 = (const float*)d_in[3];
    const float* W2 = (const float*)d_in[4];
    const float* b2 = (const float*)d_in[5];
    float* out = (float*)d_out;

    const int B = in_sizes[0] / (GN * GN);   // 4096
    gcn2_kernel<<<dim3(B), dim3(512), 0, stream>>>(a, f, W1, b1, W2, b2, out);
}

// Round 3
// 816.590 us; speedup vs baseline: 4.0917x; 4.0917x over previous
//
#include <hip/hip_runtime.h>

// 2-layer GCN, MFMA split-bf16 (hi/lo, 3-product) version. B=4096, N=116, C=116, H=128.
//
// out = relu( (Anorm @ relu(Anorm @ (f@W1) + b1)) @ W2 + b2 ),  Anorm = d (|a|+I) d
// All matmuls padded to 128x128x128, 16x16x32 bf16 MFMA, 3 products (hh, hl, lh).
//
// Per block (batch): 8 waves, wave w owns output rows [16w,16w+16).
//  - Anorm & f & v live as per-wave A-fragments in VGPRs (row = lane&15).
//  - W1/W2 pre-converted (kernel wconv) to hi/lo frag-layout in d_ws, read from L2.
//  - G -> h pass through a 64KB LDS frag buffer; C-layout -> B-layout handoff is a
//    contiguous b64 write per lane: row 16w+4g+e == 32*(w>>1) + kappa(g, 4*(w&1)+e)
//    with kappa(g,e) = 16*(e>>2) + 4*g + (e&3)  (same kappa used on every A/B side;
//    any consistent bijective k-slot mapping is valid for MFMA).
//  - v (A-operand of mm4) needs a C->A transpose: packed (hi|lo) u32 scratch with
//    XOR chunk swizzle, overlaying the (dead) frag buffer. Exactly 64KB total LDS.

typedef short short8 __attribute__((ext_vector_type(8)));
typedef float f32x4 __attribute__((ext_vector_type(4)));
typedef unsigned int uint32;

#define GN 116
#define GH 128
#define NEL (GN*GN)

union FragU { short8 s; uint32 u[4]; };

#define MFMA(A,B,C) __builtin_amdgcn_mfma_f32_16x16x32_bf16((A),(B),(C),0,0,0)

__device__ __forceinline__ uint32 pkbf(float e0, float e1){
  // low16 = bf16(e0), high16 = bf16(e1) (truncation rounding; residual goes to lo)
  return __builtin_amdgcn_perm(__float_as_uint(e1), __float_as_uint(e0), 0x07060302u);
}
__device__ __forceinline__ float hi_part(float v){
  return __uint_as_float(__float_as_uint(v) & 0xffff0000u);
}
__device__ __forceinline__ void split_pack4(const float4 v, uint32& h0, uint32& h1,
                                            uint32& l0, uint32& l1){
  h0 = pkbf(v.x, v.y);
  h1 = pkbf(v.z, v.w);
  l0 = pkbf(v.x - hi_part(v.x), v.y - hi_part(v.y));
  l1 = pkbf(v.z - hi_part(v.z), v.w - hi_part(v.w));
}

// B-from-LDS matmul: acc[nt] += A(hi/lo) x B(hi/lo), 3 products
__device__ __forceinline__ void mm_lds(const FragU* Ah, const FragU* Al,
    const unsigned short (*sBp)[32][64][8], int lane, f32x4* acc)
{
  #pragma unroll
  for (int kt = 0; kt < 4; ++kt){
    short8 bh[8], bl[8];
    #pragma unroll
    for (int nt = 0; nt < 8; ++nt){
      bh[nt] = *(const short8*)&sBp[0][kt*8+nt][lane][0];
      bl[nt] = *(const short8*)&sBp[1][kt*8+nt][lane][0];
    }
    #pragma unroll
    for (int nt = 0; nt < 8; ++nt) acc[nt] = MFMA(Ah[kt].s, bh[nt], acc[nt]);
    #pragma unroll
    for (int nt = 0; nt < 8; ++nt) acc[nt] = MFMA(Ah[kt].s, bl[nt], acc[nt]);
    #pragma unroll
    for (int nt = 0; nt < 8; ++nt) acc[nt] = MFMA(Al[kt].s, bh[nt], acc[nt]);
  }
}

// B-from-global (pre-converted W frags, L2-hot) matmul
__device__ __forceinline__ void mm_glb(const FragU* Ah, const FragU* Al,
    const unsigned short* __restrict__ Wh, const unsigned short* __restrict__ Wl,
    int lane, f32x4* acc)
{
  #pragma unroll
  for (int kt = 0; kt < 4; ++kt){
    short8 bh[8], bl[8];
    #pragma unroll
    for (int nt = 0; nt < 8; ++nt){
      const int off = ((kt*8+nt)*64 + lane)*8;
      bh[nt] = *(const short8*)(Wh + off);
      bl[nt] = *(const short8*)(Wl + off);
    }
    #pragma unroll
    for (int nt = 0; nt < 8; ++nt) acc[nt] = MFMA(Ah[kt].s, bh[nt], acc[nt]);
    #pragma unroll
    for (int nt = 0; nt < 8; ++nt) acc[nt] = MFMA(Ah[kt].s, bl[nt], acc[nt]);
    #pragma unroll
    for (int nt = 0; nt < 8; ++nt) acc[nt] = MFMA(Al[kt].s, bh[nt], acc[nt]);
  }
}

// ---- pre-convert W1,W2 into hi/lo frag layout in ws ----
// ws ushort layout: [0,16K) W1hi  [16K,32K) W1lo  [32K,48K) W2hi  [48K,64K) W2lo
// frag element index = ((kt*8+nt)*64 + lane)*8 + e ; value = W[row][col],
// row = kt*32 + 16*(e>>2) + 4*(lane>>4) + (e&3), col = nt*16 + (lane&15)
__global__ void wconv_kernel(const float* __restrict__ W1, const float* __restrict__ W2,
                             unsigned short* __restrict__ wf)
{
  const int tid  = blockIdx.x*256 + threadIdx.x;   // 0..2047
  const int lane = tid & 63;
  const int slot = tid >> 6;                       // 0..31
  const int kt = slot >> 3, nt = slot & 7;
  const int g = lane >> 4, li = lane & 15;
  const int base = (slot*64 + lane)*8;
  #pragma unroll
  for (int e = 0; e < 8; ++e){
    const int row = kt*32 + 16*(e>>2) + 4*g + (e&3);
    const int col = nt*16 + li;
    const float v1 = (row < GN) ? W1[row*GH + col] : 0.f;
    const float v2 = W2[row*GH + col];
    wf[base + e]          = (unsigned short)(__float_as_uint(v1) >> 16);
    wf[16384 + base + e]  = (unsigned short)(__float_as_uint(v1 - hi_part(v1)) >> 16);
    wf[32768 + base + e]  = (unsigned short)(__float_as_uint(v2) >> 16);
    wf[49152 + base + e]  = (unsigned short)(__float_as_uint(v2 - hi_part(v2)) >> 16);
  }
}

__global__ __launch_bounds__(512, 2) void gcn2_mfma(
    const float* __restrict__ a, const float* __restrict__ f,
    const float* __restrict__ b1v, const float* __restrict__ b2v,
    const unsigned short* __restrict__ wf, float* __restrict__ out)
{
  __shared__ __align__(16) unsigned char smem[65536];
  unsigned short (*sBp)[32][64][8] =
      reinterpret_cast<unsigned short (*)[32][64][8]>(smem); // [hl][slot][lane][e]
  float* sd = reinterpret_cast<float*>(smem);  // 128 f32; dead before first sB write

  const int t = threadIdx.x;
  const int b = blockIdx.x;
  const int lane = t & 63;
  const int w = t >> 6;          // wave 0..7
  const int g = lane >> 4;       // 0..3
  const int li = lane & 15;      // 0..15
  const float* __restrict__ ab = a + (size_t)b * NEL;
  const float* __restrict__ fb = f + (size_t)b * NEL;

  // ---- stage 1: sd[row] = rsqrt(1 + sum|a[row,:]|), rows>=116 -> 0 ----
  #pragma unroll
  for (int pass = 0; pass < 2; ++pass){
    const int row = (t >> 3) + pass*64;
    const int s = t & 7;
    if (row < 128){
      if (row < GN){
        float sum = 0.f;
        #pragma unroll
        for (int q = 0; q < 4; ++q){
          const int c4 = 4*(s + 8*q);
          if (c4 < GN){
            const float4 v = *(const float4*)(ab + row*GN + c4);
            sum += fabsf(v.x) + fabsf(v.y) + fabsf(v.z) + fabsf(v.w);
          }
        }
        sum += __shfl_xor(sum, 1, 64);
        sum += __shfl_xor(sum, 2, 64);
        sum += __shfl_xor(sum, 4, 64);
        if (s == 0) sd[row] = rsqrtf(sum + 1.0f);
      } else {
        if (s == 0) sd[row] = 0.f;
      }
    }
  }
  __syncthreads();                                          // B1: sd ready

  // ---- build per-wave A-fragments: f (for mm1) and Anorm (for mm2/mm3) ----
  const int irow = 16*w + li;
  const bool rvalid = irow < GN;
  FragU fh[4], fl[4], ah[4], al[4];
  const float di = rvalid ? sd[irow] : 0.f;
  #pragma unroll
  for (int kt = 0; kt < 4; ++kt){
    #pragma unroll
    for (int hi = 0; hi < 2; ++hi){
      const int colb = kt*32 + 16*hi + 4*g;      // multiple of 4; 116%4==0 -> clean
      const bool cvalid = colb < GN;
      float4 vf = {0.f,0.f,0.f,0.f}, va = {0.f,0.f,0.f,0.f};
      if (rvalid && cvalid){
        vf = *(const float4*)(fb + irow*GN + colb);
        va = *(const float4*)(ab + irow*GN + colb);
      }
      const float4 dc = *(const float4*)(sd + colb);  // colb<=124, sd[>=116]=0
      float4 na;
      na.x = di * (fabsf(va.x) + ((colb+0)==irow ? 1.f : 0.f)) * dc.x;
      na.y = di * (fabsf(va.y) + ((colb+1)==irow ? 1.f : 0.f)) * dc.y;
      na.z = di * (fabsf(va.z) + ((colb+2)==irow ? 1.f : 0.f)) * dc.z;
      na.w = di * (fabsf(va.w) + ((colb+3)==irow ? 1.f : 0.f)) * dc.w;
      split_pack4(vf, fh[kt].u[2*hi+0], fh[kt].u[2*hi+1], fl[kt].u[2*hi+0], fl[kt].u[2*hi+1]);
      split_pack4(na, ah[kt].u[2*hi+0], ah[kt].u[2*hi+1], al[kt].u[2*hi+0], al[kt].u[2*hi+1]);
    }
  }

  // ---- mm1: G = f @ W1 (B = pre-converted global frags) ----
  f32x4 acc[8];
  #pragma unroll
  for (int nt = 0; nt < 8; ++nt) acc[nt] = (f32x4){0.f,0.f,0.f,0.f};
  mm_glb(fh, fl, wf, wf + 16384, lane, acc);

  __syncthreads();                                          // B2: sd dead, LDS writable

  // ---- G -> LDS frag buffer (hi/lo). rows>=116 already 0 (zeroed f frags). ----
  const int slotw = w >> 1;   // kt of this wave's rows
  const int hh = w & 1;       // which b64 half of the 16B lane slot
  #pragma unroll
  for (int nt = 0; nt < 8; ++nt){
    uint32* ph = (uint32*)&sBp[0][slotw*8+nt][lane][4*hh];
    uint32* pl = (uint32*)&sBp[1][slotw*8+nt][lane][4*hh];
    const float x0 = acc[nt][0], x1 = acc[nt][1], x2 = acc[nt][2], x3 = acc[nt][3];
    ph[0] = pkbf(x0, x1);
    ph[1] = pkbf(x2, x3);
    pl[0] = pkbf(x0 - hi_part(x0), x1 - hi_part(x1));
    pl[1] = pkbf(x2 - hi_part(x2), x3 - hi_part(x3));
  }
  __syncthreads();                                          // B3: G frags ready

  // ---- mm2: h = relu(Anorm @ G + b1) ----
  #pragma unroll
  for (int nt = 0; nt < 8; ++nt) acc[nt] = (f32x4){0.f,0.f,0.f,0.f};
  mm_lds(ah, al, sBp, lane, acc);

  __syncthreads();                                          // B4: all done reading G
  #pragma unroll
  for (int nt = 0; nt < 8; ++nt){
    const float bias = b1v[nt*16 + li];
    float hv[4];
    #pragma unroll
    for (int e = 0; e < 4; ++e){
      const int r = 16*w + 4*g + e;
      hv[e] = (r < GN) ? fmaxf(acc[nt][e] + bias, 0.f) : 0.f;  // zero padded rows!
    }
    uint32* ph = (uint32*)&sBp[0][slotw*8+nt][lane][4*hh];
    uint32* pl = (uint32*)&sBp[1][slotw*8+nt][lane][4*hh];
    ph[0] = pkbf(hv[0], hv[1]);
    ph[1] = pkbf(hv[2], hv[3]);
    pl[0] = pkbf(hv[0] - hi_part(hv[0]), hv[1] - hi_part(hv[1]));
    pl[1] = pkbf(hv[2] - hi_part(hv[2]), hv[3] - hi_part(hv[3]));
  }
  __syncthreads();                                          // B5: h frags ready

  // ---- mm3: v = Anorm @ h ----
  #pragma unroll
  for (int nt = 0; nt < 8; ++nt) acc[nt] = (f32x4){0.f,0.f,0.f,0.f};
  mm_lds(ah, al, sBp, lane, acc);

  __syncthreads();                                          // B6: all done reading h

  // ---- v -> per-wave packed (hi|lo) scratch with XOR chunk swizzle ----
  // scr[r][c] at word r*128 + (c ^ ((r&7)<<2)); exactly overlays the 64KB buffer
  uint32* scr = reinterpret_cast<uint32*>(smem + (size_t)w * 8192);
  #pragma unroll
  for (int nt = 0; nt < 8; ++nt){
    #pragma unroll
    for (int e = 0; e < 4; ++e){
      const int r = 4*g + e;                 // local row 0..15
      const int col = 16*nt + li;
      const float v = acc[nt][e];            // rows>=116 are naturally 0
      const uint32 hb = __float_as_uint(v) >> 16;
      const uint32 lb = __float_as_uint(v - hi_part(v)) >> 16;
      scr[r*128 + (col ^ ((r & 7) << 2))] = hb | (lb << 16);
    }
  }
  __syncthreads();                                          // B7: scratch ready

  // ---- read back v as A-fragments (unpack via v_perm) ----
  FragU vh[4], vl[4];
  {
    const int sw = (li & 7) << 2;
    #pragma unroll
    for (int kt = 0; kt < 4; ++kt){
      #pragma unroll
      for (int hi = 0; hi < 2; ++hi){
        const int cb = (kt*32 + 16*hi + 4*g) ^ sw;   // stays 4-word aligned
        const uint32* p = scr + li*128 + cb;
        const uint32 q0 = p[0], q1 = p[1], q2 = p[2], q3 = p[3];
        vh[kt].u[2*hi+0] = __builtin_amdgcn_perm(q1, q0, 0x05040100u); // low halves
        vh[kt].u[2*hi+1] = __builtin_amdgcn_perm(q3, q2, 0x05040100u);
        vl[kt].u[2*hi+0] = __builtin_amdgcn_perm(q1, q0, 0x07060302u); // high halves
        vl[kt].u[2*hi+1] = __builtin_amdgcn_perm(q3, q2, 0x07060302u);
      }
    }
  }

  // ---- mm4: out = relu(v @ W2 + b2) ----
  #pragma unroll
  for (int nt = 0; nt < 8; ++nt) acc[nt] = (f32x4){0.f,0.f,0.f,0.f};
  mm_glb(vh, vl, wf + 32768, wf + 49152, lane, acc);

  float* __restrict__ ob = out + (size_t)b * (GN*GH);
  #pragma unroll
  for (int nt = 0; nt < 8; ++nt){
    const float bias = b2v[nt*16 + li];
    #pragma unroll
    for (int e = 0; e < 4; ++e){
      const int r = 16*w + 4*g + e;
      if (r < GN)
        ob[r*GH + 16*nt + li] = fmaxf(acc[nt][e] + bias, 0.f);
    }
  }
}

extern "C" void kernel_launch(void* const* d_in, const int* in_sizes, int n_in,
                              void* d_out, int out_size, void* d_ws, size_t ws_size,
                              hipStream_t stream) {
  const float* a  = (const float*)d_in[0];
  const float* f  = (const float*)d_in[1];
  const float* W1 = (const float*)d_in[2];
  const float* b1 = (const float*)d_in[3];
  const float* W2 = (const float*)d_in[4];
  const float* b2 = (const float*)d_in[5];
  float* out = (float*)d_out;
  unsigned short* wf = (unsigned short*)d_ws;   // needs 131072 bytes

  const int B = in_sizes[0] / NEL;              // 4096
  wconv_kernel<<<8, 256, 0, stream>>>(W1, W2, wf);
  gcn2_mfma<<<B, 512, 0, stream>>>(a, f, b1, b2, wf, out);
}